// Round 2
// baseline (732.172 us; speedup 1.0000x reference)
//
#include <hip/hip_runtime.h>
#include <cstdint>

// IFS fractal step (all float32):
//   tp = selu(points @ M[choice] + b[choice])         -> out[0 .. N*3)
//   new_colors = (prev_colors + colors[choice]) * 0.5 -> out[N*3 .. 2*N*3)
// Memory-bound: 872 MB total traffic, floor ~140 us @ 6.3 TB/s.
// Loads stay CACHED: the 48B-stride float4 read pattern relies on intra-wave
// L1/L2 line reuse (NT loads regressed +30us in round 1).
// Stores are NON-TEMPORAL: 402 MB written once, never re-read — evict-first
// keeps L2 free for the input streams.

typedef float v4f __attribute__((ext_vector_type(4)));

__device__ __forceinline__ float selu_f(float x) {
    const float alpha = 1.6732632423543772f;
    const float scale = 1.0507009873554805f;
    float neg = alpha * (__expf(x) - 1.0f);   // only used for x <= 0
    return scale * (x > 0.0f ? x : neg);
}

__global__ __launch_bounds__(256) void ifs_kernel(
    const float* __restrict__ points,       // [N,3]
    const float* __restrict__ prev_colors,  // [N,3]
    const int*   __restrict__ choices,      // [N]
    const float* __restrict__ matrices,     // [K,3,3] k*9 + d*3 + e
    const float* __restrict__ biases,       // [K,3]
    const float* __restrict__ colors,       // [K,3]
    float* __restrict__ out_tp,             // [N,3]
    float* __restrict__ out_col,            // [N,3]
    long long n_points)
{
    // LDS transform table, stride 17 floats: (17k + j) % 32 distinct for all k in [0,8)
    __shared__ float T[8][17];
    int tid = threadIdx.x;
    if (tid < 8 * 16) {
        int k = tid >> 4, j = tid & 15;
        float v = 0.0f;
        if (j < 9)       v = matrices[k * 9 + j];
        else if (j < 12) v = biases[k * 3 + (j - 9)];
        else if (j < 15) v = colors[k * 3 + (j - 12)];
        T[k][j] = v;
    }
    __syncthreads();

    long long g = (long long)blockIdx.x * blockDim.x + tid;
    long long base = g * 4;  // 4 points per thread
    if (base >= n_points) return;

    if (base + 4 <= n_points) {
        // points/prev_colors: 12 floats = 3x float4; choices: 1x int4 (cached loads)
        float4 pv[3], cv[3];
        const float4* pp = reinterpret_cast<const float4*>(points + base * 3);
        const float4* pc = reinterpret_cast<const float4*>(prev_colors + base * 3);
        const int4*   cc = reinterpret_cast<const int4*>(choices + base);
        pv[0] = pp[0]; pv[1] = pp[1]; pv[2] = pp[2];
        cv[0] = pc[0]; cv[1] = pc[1]; cv[2] = pc[2];
        int4 ch = cc[0];

        const float* pb = reinterpret_cast<const float*>(pv);
        const float* cb = reinterpret_cast<const float*>(cv);
        const int*   ci = reinterpret_cast<const int*>(&ch);

        v4f ov[3], oc[3];
        float* ob  = reinterpret_cast<float*>(ov);
        float* ocb = reinterpret_cast<float*>(oc);

        #pragma unroll
        for (int j = 0; j < 4; ++j) {
            int k = ci[j] & 7;
            const float* t = T[k];
            float x = pb[3 * j + 0];
            float y = pb[3 * j + 1];
            float z = pb[3 * j + 2];
            // tp[e] = sum_d p[d] * M[d*3+e] + b[e]   (contract over FIRST axis of M)
            float e0 = fmaf(x, t[0], fmaf(y, t[3], fmaf(z, t[6], t[9])));
            float e1 = fmaf(x, t[1], fmaf(y, t[4], fmaf(z, t[7], t[10])));
            float e2 = fmaf(x, t[2], fmaf(y, t[5], fmaf(z, t[8], t[11])));
            ob[3 * j + 0] = selu_f(e0);
            ob[3 * j + 1] = selu_f(e1);
            ob[3 * j + 2] = selu_f(e2);
            ocb[3 * j + 0] = (cb[3 * j + 0] + t[12]) * 0.5f;
            ocb[3 * j + 1] = (cb[3 * j + 1] + t[13]) * 0.5f;
            ocb[3 * j + 2] = (cb[3 * j + 2] + t[14]) * 0.5f;
        }

        // Non-temporal stores: write-once streams, keep them out of L2.
        v4f* ot = reinterpret_cast<v4f*>(out_tp + base * 3);
        v4f* oo = reinterpret_cast<v4f*>(out_col + base * 3);
        __builtin_nontemporal_store(ov[0], ot + 0);
        __builtin_nontemporal_store(ov[1], ot + 1);
        __builtin_nontemporal_store(ov[2], ot + 2);
        __builtin_nontemporal_store(oc[0], oo + 0);
        __builtin_nontemporal_store(oc[1], oo + 1);
        __builtin_nontemporal_store(oc[2], oo + 2);
    } else {
        // scalar tail
        for (long long p = base; p < n_points; ++p) {
            int k = choices[p] & 7;
            const float* t = T[k];
            float x = points[p * 3 + 0];
            float y = points[p * 3 + 1];
            float z = points[p * 3 + 2];
            float e0 = fmaf(x, t[0], fmaf(y, t[3], fmaf(z, t[6], t[9])));
            float e1 = fmaf(x, t[1], fmaf(y, t[4], fmaf(z, t[7], t[10])));
            float e2 = fmaf(x, t[2], fmaf(y, t[5], fmaf(z, t[8], t[11])));
            out_tp[p * 3 + 0] = selu_f(e0);
            out_tp[p * 3 + 1] = selu_f(e1);
            out_tp[p * 3 + 2] = selu_f(e2);
            out_col[p * 3 + 0] = (prev_colors[p * 3 + 0] + t[12]) * 0.5f;
            out_col[p * 3 + 1] = (prev_colors[p * 3 + 1] + t[13]) * 0.5f;
            out_col[p * 3 + 2] = (prev_colors[p * 3 + 2] + t[14]) * 0.5f;
        }
    }
}

extern "C" void kernel_launch(void* const* d_in, const int* in_sizes, int n_in,
                              void* d_out, int out_size, void* d_ws, size_t ws_size,
                              hipStream_t stream) {
    const float* points      = (const float*)d_in[0];
    const float* prev_colors = (const float*)d_in[1];
    const int*   choices     = (const int*)d_in[2];
    const float* matrices    = (const float*)d_in[3];
    const float* biases      = (const float*)d_in[4];
    const float* colors      = (const float*)d_in[5];

    long long n = in_sizes[2];  // choices: one per point
    float* out_tp  = (float*)d_out;
    float* out_col = out_tp + (size_t)n * 3;

    long long n_threads = (n + 3) / 4;
    int block = 256;
    long long grid = (n_threads + block - 1) / block;
    ifs_kernel<<<(dim3)(unsigned int)grid, block, 0, stream>>>(
        points, prev_colors, choices, matrices, biases, colors,
        out_tp, out_col, n);
}

// Round 3
// 673.423 us; speedup vs baseline: 1.0872x; 1.0872x over previous
//
#include <hip/hip_runtime.h>
#include <cstdint>

// IFS fractal step (all float32):
//   tp = selu(points @ M[choice] + b[choice])         -> out[0 .. N*3)
//   new_colors = (prev_colors + colors[choice]) * 0.5 -> out[N*3 .. 2*N*3)
//
// R2 lesson: NT stores caused partial-line writebacks (WRITE_SIZE 402->510MB,
// kernel 182->265us). All accesses CACHED (L2 merges the stride-48B pieces).
//
// This round: dense-per-instruction addressing. One float4 of the flat [3N]
// stream per lane (16B lane stride -> each vmem instruction covers a
// contiguous 1KB / 16 lines, vs 48 lines for the old 48B-stride layout).
// Each output float4 [4W..4W+3] spans exactly 2 points p=floor(4W/3), q=p+1;
// their xyz come from float4s W-1,W,W+1 (dense loads, mutual L1 hits).
// Component routing by phase phi = W%3 via branchless selects (compile-time
// indices only). Math is bit-identical to the baseline (same fmaf chains).

__device__ __forceinline__ float selu_f(float x) {
    const float alpha = 1.6732632423543772f;
    const float scale = 1.0507009873554805f;
    float neg = alpha * (__expf(x) - 1.0f);   // only used for x <= 0
    return scale * (x > 0.0f ? x : neg);
}

__global__ __launch_bounds__(256) void ifs_phase_kernel(
    const float4* __restrict__ pts4,    // points as [3N/4] float4
    const float4* __restrict__ pcol4,   // prev_colors as [3N/4] float4
    const int*   __restrict__ choices,  // [N]
    const float* __restrict__ matrices, // [K,3,3] k*9 + d*3 + e
    const float* __restrict__ biases,   // [K,3]
    const float* __restrict__ colors,   // [K,3]
    float4* __restrict__ out_tp4,       // [3N/4]
    float4* __restrict__ out_col4,      // [3N/4]
    int F)                              // = 3N/4  (N % 4 == 0, so F % 3 == 0)
{
    // LDS transform table, stride 17 floats: (17k + j) % 32 distinct for all k
    __shared__ float T[8][17];
    int tid = threadIdx.x;
    if (tid < 8 * 16) {
        int k = tid >> 4, j = tid & 15;
        float v = 0.0f;
        if (j < 9)       v = matrices[k * 9 + j];
        else if (j < 12) v = biases[k * 3 + (j - 9)];
        else if (j < 15) v = colors[k * 3 + (j - 12)];
        T[k][j] = v;
    }
    __syncthreads();

    int W = blockIdx.x * 256 + tid;
    if (W >= F) return;

    int t3  = W / 3;          // magic-mul
    int phi = W - 3 * t3;     // W mod 3 == (4W) mod 3
    int p   = W + t3;         // floor(4W/3); q = p+1 (q's float4-window
                              // membership implies q <= N-1, proven)
    int Wm = (W == 0)     ? 0     : W - 1;   // A unused when W==0 (phi==0)
    int Wp = (W + 1 < F)  ? W + 1 : F - 1;   // C unused when W==F-1 (phi==2, F%3==0)

    // Window floats w[0..11] = A(4W-4..), B(4W..), C(4W+4..). All dense loads.
    float4 A  = pts4[Wm],  B  = pts4[W],  C  = pts4[Wp];
    float4 Ga = pcol4[Wm], Gb = pcol4[W], Gc = pcol4[Wp];
    int kp = choices[p] & 7;
    int kq = choices[p + 1] & 7;

    bool e0 = (phi == 0), e1 = (phi == 1);

    // p.xyz = w[4-phi .. 6-phi], q.xyz = w[7-phi .. 9-phi]
    float px = e0 ? B.x : e1 ? A.w : A.z;
    float py = e0 ? B.y : e1 ? B.x : A.w;
    float pz = e0 ? B.z : e1 ? B.y : B.x;
    float qx = e0 ? B.w : e1 ? B.z : B.y;
    float qy = e0 ? C.x : e1 ? B.w : B.z;
    float qz = e0 ? C.y : e1 ? C.x : B.w;

    float gpx = e0 ? Gb.x : e1 ? Ga.w : Ga.z;
    float gpy = e0 ? Gb.y : e1 ? Gb.x : Ga.w;
    float gpz = e0 ? Gb.z : e1 ? Gb.y : Gb.x;
    float gqx = e0 ? Gb.w : e1 ? Gb.z : Gb.y;
    float gqy = e0 ? Gc.x : e1 ? Gb.w : Gb.z;
    float gqz = e0 ? Gc.y : e1 ? Gc.x : Gb.w;

    const float* tp_ = T[kp];
    const float* tq_ = T[kq];

    // tp[e] = sum_d pt[d] * M[d*3+e] + b[e]  (contract over FIRST axis of M)
    float sp0 = selu_f(fmaf(px, tp_[0], fmaf(py, tp_[3], fmaf(pz, tp_[6], tp_[9]))));
    float sp1 = selu_f(fmaf(px, tp_[1], fmaf(py, tp_[4], fmaf(pz, tp_[7], tp_[10]))));
    float sp2 = selu_f(fmaf(px, tp_[2], fmaf(py, tp_[5], fmaf(pz, tp_[8], tp_[11]))));
    float sq0 = selu_f(fmaf(qx, tq_[0], fmaf(qy, tq_[3], fmaf(qz, tq_[6], tq_[9]))));
    float sq1 = selu_f(fmaf(qx, tq_[1], fmaf(qy, tq_[4], fmaf(qz, tq_[7], tq_[10]))));
    float sq2 = selu_f(fmaf(qx, tq_[2], fmaf(qy, tq_[5], fmaf(qz, tq_[8], tq_[11]))));

    float cp0 = (gpx + tp_[12]) * 0.5f;
    float cp1 = (gpy + tp_[13]) * 0.5f;
    float cp2 = (gpz + tp_[14]) * 0.5f;
    float cq0 = (gqx + tq_[12]) * 0.5f;
    float cq1 = (gqy + tq_[13]) * 0.5f;
    float cq2 = (gqz + tq_[14]) * 0.5f;

    // out window [4W..4W+3] = comps [phi..phi+3] of [p0,p1,p2,q0,q1,q2]
    float4 o, oc;
    o.x  = e0 ? sp0 : e1 ? sp1 : sp2;
    o.y  = e0 ? sp1 : e1 ? sp2 : sq0;
    o.z  = e0 ? sp2 : e1 ? sq0 : sq1;
    o.w  = e0 ? sq0 : e1 ? sq1 : sq2;
    oc.x = e0 ? cp0 : e1 ? cp1 : cp2;
    oc.y = e0 ? cp1 : e1 ? cp2 : cq0;
    oc.z = e0 ? cp2 : e1 ? cq0 : cq1;
    oc.w = e0 ? cq0 : e1 ? cq1 : cq2;

    out_tp4[W]  = o;   // dense 1KB/wave store
    out_col4[W] = oc;  // dense 1KB/wave store
}

// Generic fallback (any n): one point per thread, scalar. Only used if n%4 != 0.
__global__ __launch_bounds__(256) void ifs_scalar_kernel(
    const float* __restrict__ points, const float* __restrict__ prev_colors,
    const int* __restrict__ choices, const float* __restrict__ matrices,
    const float* __restrict__ biases, const float* __restrict__ colors,
    float* __restrict__ out_tp, float* __restrict__ out_col, long long n_points)
{
    long long p = (long long)blockIdx.x * blockDim.x + threadIdx.x;
    if (p >= n_points) return;
    int k = choices[p] & 7;
    const float* M = matrices + k * 9;
    float x = points[p * 3 + 0], y = points[p * 3 + 1], z = points[p * 3 + 2];
    float e0 = fmaf(x, M[0], fmaf(y, M[3], fmaf(z, M[6], biases[k * 3 + 0])));
    float e1 = fmaf(x, M[1], fmaf(y, M[4], fmaf(z, M[7], biases[k * 3 + 1])));
    float e2 = fmaf(x, M[2], fmaf(y, M[5], fmaf(z, M[8], biases[k * 3 + 2])));
    out_tp[p * 3 + 0] = selu_f(e0);
    out_tp[p * 3 + 1] = selu_f(e1);
    out_tp[p * 3 + 2] = selu_f(e2);
    out_col[p * 3 + 0] = (prev_colors[p * 3 + 0] + colors[k * 3 + 0]) * 0.5f;
    out_col[p * 3 + 1] = (prev_colors[p * 3 + 1] + colors[k * 3 + 1]) * 0.5f;
    out_col[p * 3 + 2] = (prev_colors[p * 3 + 2] + colors[k * 3 + 2]) * 0.5f;
}

extern "C" void kernel_launch(void* const* d_in, const int* in_sizes, int n_in,
                              void* d_out, int out_size, void* d_ws, size_t ws_size,
                              hipStream_t stream) {
    const float* points      = (const float*)d_in[0];
    const float* prev_colors = (const float*)d_in[1];
    const int*   choices     = (const int*)d_in[2];
    const float* matrices    = (const float*)d_in[3];
    const float* biases      = (const float*)d_in[4];
    const float* colors      = (const float*)d_in[5];

    long long n = in_sizes[2];  // choices: one per point
    float* out_tp  = (float*)d_out;
    float* out_col = out_tp + (size_t)n * 3;

    if ((n & 3LL) == 0) {
        int F = (int)(n / 4 * 3);   // float4s per stream; F % 3 == 0
        int block = 256;
        int grid = (F + block - 1) / block;
        ifs_phase_kernel<<<grid, block, 0, stream>>>(
            (const float4*)points, (const float4*)prev_colors, choices,
            matrices, biases, colors,
            (float4*)out_tp, (float4*)out_col, F);
    } else {
        int block = 256;
        long long grid = (n + block - 1) / block;
        ifs_scalar_kernel<<<(dim3)(unsigned int)grid, block, 0, stream>>>(
            points, prev_colors, choices, matrices, biases, colors,
            out_tp, out_col, n);
    }
}

// Round 4
// 671.009 us; speedup vs baseline: 1.0912x; 1.0036x over previous
//
#include <hip/hip_runtime.h>
#include <cstdint>

// IFS fractal step (all float32):
//   tp = selu(points @ M[choice] + b[choice])         -> out[0 .. N*3)
//   new_colors = (prev_colors + colors[choice]) * 0.5 -> out[N*3 .. 2*N*3)
//
// R3 structure (dense per-instruction addressing, cached loads+stores) kept.
// R4 change: ILP=2 — each thread handles two independent float4 windows
// W and W+H (H = F/2, H%3==0 so both share phase phi). choices loads issued
// first (they gate the longest dep chain: choices -> LDS T reads -> fma).
// Doubles in-flight memory chains per wave; halves blocks/barriers.

__device__ __forceinline__ float selu_f(float x) {
    const float alpha = 1.6732632423543772f;
    const float scale = 1.0507009873554805f;
    float neg = alpha * (__expf(x) - 1.0f);   // only used for x <= 0
    return scale * (x > 0.0f ? x : neg);
}

// Compute one output window [4W..4W+3] of both streams.
// Window floats w[0..11] = A(4W-4..), B(4W..), C(4W+4..);
// p.xyz = w[4-phi..6-phi], q.xyz = w[7-phi..9-phi];
// out comps = [phi..phi+3] of [p0,p1,p2,q0,q1,q2]. Same math as R3 (verified).
__device__ __forceinline__ void win_compute(
    const float (*T)[17], int kp, int kq, bool e0, bool e1,
    const float4& A, const float4& B, const float4& C,
    const float4& Ga, const float4& Gb, const float4& Gc,
    float4& o, float4& oc)
{
    float px = e0 ? B.x : e1 ? A.w : A.z;
    float py = e0 ? B.y : e1 ? B.x : A.w;
    float pz = e0 ? B.z : e1 ? B.y : B.x;
    float qx = e0 ? B.w : e1 ? B.z : B.y;
    float qy = e0 ? C.x : e1 ? B.w : B.z;
    float qz = e0 ? C.y : e1 ? C.x : B.w;

    float gpx = e0 ? Gb.x : e1 ? Ga.w : Ga.z;
    float gpy = e0 ? Gb.y : e1 ? Gb.x : Ga.w;
    float gpz = e0 ? Gb.z : e1 ? Gb.y : Gb.x;
    float gqx = e0 ? Gb.w : e1 ? Gb.z : Gb.y;
    float gqy = e0 ? Gc.x : e1 ? Gb.w : Gb.z;
    float gqz = e0 ? Gc.y : e1 ? Gc.x : Gb.w;

    const float* tp_ = T[kp];
    const float* tq_ = T[kq];

    // tp[e] = sum_d pt[d] * M[d*3+e] + b[e]  (contract over FIRST axis of M)
    float sp0 = selu_f(fmaf(px, tp_[0], fmaf(py, tp_[3], fmaf(pz, tp_[6], tp_[9]))));
    float sp1 = selu_f(fmaf(px, tp_[1], fmaf(py, tp_[4], fmaf(pz, tp_[7], tp_[10]))));
    float sp2 = selu_f(fmaf(px, tp_[2], fmaf(py, tp_[5], fmaf(pz, tp_[8], tp_[11]))));
    float sq0 = selu_f(fmaf(qx, tq_[0], fmaf(qy, tq_[3], fmaf(qz, tq_[6], tq_[9]))));
    float sq1 = selu_f(fmaf(qx, tq_[1], fmaf(qy, tq_[4], fmaf(qz, tq_[7], tq_[10]))));
    float sq2 = selu_f(fmaf(qx, tq_[2], fmaf(qy, tq_[5], fmaf(qz, tq_[8], tq_[11]))));

    float cp0 = (gpx + tp_[12]) * 0.5f;
    float cp1 = (gpy + tp_[13]) * 0.5f;
    float cp2 = (gpz + tp_[14]) * 0.5f;
    float cq0 = (gqx + tq_[12]) * 0.5f;
    float cq1 = (gqy + tq_[13]) * 0.5f;
    float cq2 = (gqz + tq_[14]) * 0.5f;

    o.x  = e0 ? sp0 : e1 ? sp1 : sp2;
    o.y  = e0 ? sp1 : e1 ? sp2 : sq0;
    o.z  = e0 ? sp2 : e1 ? sq0 : sq1;
    o.w  = e0 ? sq0 : e1 ? sq1 : sq2;
    oc.x = e0 ? cp0 : e1 ? cp1 : cp2;
    oc.y = e0 ? cp1 : e1 ? cp2 : cq0;
    oc.z = e0 ? cp2 : e1 ? cq0 : cq1;
    oc.w = e0 ? cq0 : e1 ? cq1 : cq2;
}

// ILP=2 kernel: requires F = 2H with H % 3 == 0  (i.e. N % 8 == 0).
__global__ __launch_bounds__(256) void ifs_phase2_kernel(
    const float4* __restrict__ pts4,    // [F]
    const float4* __restrict__ pcol4,   // [F]
    const int*   __restrict__ choices,  // [N]
    const float* __restrict__ matrices, // [K,3,3]
    const float* __restrict__ biases,   // [K,3]
    const float* __restrict__ colors,   // [K,3]
    float4* __restrict__ out_tp4,       // [F]
    float4* __restrict__ out_col4,      // [F]
    int H)                              // F/2
{
    __shared__ float T[8][17];  // stride 17: (17k+j)%32 distinct for k in [0,8)
    int tid = threadIdx.x;
    if (tid < 8 * 16) {
        int k = tid >> 4, j = tid & 15;
        float v = 0.0f;
        if (j < 9)       v = matrices[k * 9 + j];
        else if (j < 12) v = biases[k * 3 + (j - 9)];
        else if (j < 15) v = colors[k * 3 + (j - 12)];
        T[k][j] = v;
    }
    __syncthreads();

    int W0 = blockIdx.x * 256 + tid;
    if (W0 >= H) return;
    int W1 = W0 + H;          // phi(W1) == phi(W0) since H % 3 == 0
    int F  = 2 * H;

    int t3  = W0 / 3;         // magic-mul
    int phi = W0 - 3 * t3;
    int p0  = W0 + t3;        // floor(4*W0/3); q0 = p0+1 always in-bounds
    int p1  = W1 + W1 / 3;
    bool e0 = (phi == 0), e1 = (phi == 1);

    // choices first: they gate the longest chain (choices -> T ds_read -> fma)
    int kp0 = choices[p0]     & 7;
    int kq0 = choices[p0 + 1] & 7;
    int kp1 = choices[p1]     & 7;
    int kq1 = choices[p1 + 1] & 7;

    // Window neighbors. W0+1 <= H < F always valid; W1-1 >= H-1 >= 0 valid.
    int Wm0 = (W0 == 0)    ? 0     : W0 - 1;  // A0 unused when W0==0 (phi==0)
    int Wp1 = (W1 + 1 < F) ? W1 + 1 : F - 1;  // C1 unused when W1==F-1 (phi==2)

    float4 A0 = pts4[Wm0],  B0 = pts4[W0],  C0 = pts4[W0 + 1];
    float4 A1 = pts4[W1-1], B1 = pts4[W1],  C1 = pts4[Wp1];
    float4 Ga0 = pcol4[Wm0],  Gb0 = pcol4[W0], Gc0 = pcol4[W0 + 1];
    float4 Ga1 = pcol4[W1-1], Gb1 = pcol4[W1], Gc1 = pcol4[Wp1];

    float4 o0, oc0, o1, oc1;
    win_compute(T, kp0, kq0, e0, e1, A0, B0, C0, Ga0, Gb0, Gc0, o0, oc0);
    win_compute(T, kp1, kq1, e0, e1, A1, B1, C1, Ga1, Gb1, Gc1, o1, oc1);

    out_tp4[W0]  = o0;
    out_col4[W0] = oc0;
    out_tp4[W1]  = o1;
    out_col4[W1] = oc1;
}

// R3 single-window kernel (verified) — fallback for N%4==0 && N%8!=0.
__global__ __launch_bounds__(256) void ifs_phase_kernel(
    const float4* __restrict__ pts4, const float4* __restrict__ pcol4,
    const int* __restrict__ choices, const float* __restrict__ matrices,
    const float* __restrict__ biases, const float* __restrict__ colors,
    float4* __restrict__ out_tp4, float4* __restrict__ out_col4, int F)
{
    __shared__ float T[8][17];
    int tid = threadIdx.x;
    if (tid < 8 * 16) {
        int k = tid >> 4, j = tid & 15;
        float v = 0.0f;
        if (j < 9)       v = matrices[k * 9 + j];
        else if (j < 12) v = biases[k * 3 + (j - 9)];
        else if (j < 15) v = colors[k * 3 + (j - 12)];
        T[k][j] = v;
    }
    __syncthreads();

    int W = blockIdx.x * 256 + tid;
    if (W >= F) return;
    int t3  = W / 3;
    int phi = W - 3 * t3;
    int p   = W + t3;
    bool e0 = (phi == 0), e1 = (phi == 1);
    int kp = choices[p] & 7, kq = choices[p + 1] & 7;
    int Wm = (W == 0)    ? 0     : W - 1;
    int Wp = (W + 1 < F) ? W + 1 : F - 1;
    float4 A = pts4[Wm], B = pts4[W], C = pts4[Wp];
    float4 Ga = pcol4[Wm], Gb = pcol4[W], Gc = pcol4[Wp];
    float4 o, oc;
    win_compute(T, kp, kq, e0, e1, A, B, C, Ga, Gb, Gc, o, oc);
    out_tp4[W]  = o;
    out_col4[W] = oc;
}

// Generic fallback (any n): one point per thread, scalar.
__global__ __launch_bounds__(256) void ifs_scalar_kernel(
    const float* __restrict__ points, const float* __restrict__ prev_colors,
    const int* __restrict__ choices, const float* __restrict__ matrices,
    const float* __restrict__ biases, const float* __restrict__ colors,
    float* __restrict__ out_tp, float* __restrict__ out_col, long long n_points)
{
    long long p = (long long)blockIdx.x * blockDim.x + threadIdx.x;
    if (p >= n_points) return;
    int k = choices[p] & 7;
    const float* M = matrices + k * 9;
    float x = points[p * 3 + 0], y = points[p * 3 + 1], z = points[p * 3 + 2];
    float e0 = fmaf(x, M[0], fmaf(y, M[3], fmaf(z, M[6], biases[k * 3 + 0])));
    float e1 = fmaf(x, M[1], fmaf(y, M[4], fmaf(z, M[7], biases[k * 3 + 1])));
    float e2 = fmaf(x, M[2], fmaf(y, M[5], fmaf(z, M[8], biases[k * 3 + 2])));
    out_tp[p * 3 + 0] = selu_f(e0);
    out_tp[p * 3 + 1] = selu_f(e1);
    out_tp[p * 3 + 2] = selu_f(e2);
    out_col[p * 3 + 0] = (prev_colors[p * 3 + 0] + colors[k * 3 + 0]) * 0.5f;
    out_col[p * 3 + 1] = (prev_colors[p * 3 + 1] + colors[k * 3 + 1]) * 0.5f;
    out_col[p * 3 + 2] = (prev_colors[p * 3 + 2] + colors[k * 3 + 2]) * 0.5f;
}

extern "C" void kernel_launch(void* const* d_in, const int* in_sizes, int n_in,
                              void* d_out, int out_size, void* d_ws, size_t ws_size,
                              hipStream_t stream) {
    const float* points      = (const float*)d_in[0];
    const float* prev_colors = (const float*)d_in[1];
    const int*   choices     = (const int*)d_in[2];
    const float* matrices    = (const float*)d_in[3];
    const float* biases      = (const float*)d_in[4];
    const float* colors      = (const float*)d_in[5];

    long long n = in_sizes[2];  // choices: one per point
    float* out_tp  = (float*)d_out;
    float* out_col = out_tp + (size_t)n * 3;

    int block = 256;
    if ((n & 7LL) == 0 && n > 0) {
        // F = 3n/4 divisible by 6 -> H = F/2 with H%3==0
        int H = (int)(n / 8 * 3);
        int grid = (H + block - 1) / block;
        ifs_phase2_kernel<<<grid, block, 0, stream>>>(
            (const float4*)points, (const float4*)prev_colors, choices,
            matrices, biases, colors, (float4*)out_tp, (float4*)out_col, H);
    } else if ((n & 3LL) == 0 && n > 0) {
        int F = (int)(n / 4 * 3);
        int grid = (F + block - 1) / block;
        ifs_phase_kernel<<<grid, block, 0, stream>>>(
            (const float4*)points, (const float4*)prev_colors, choices,
            matrices, biases, colors, (float4*)out_tp, (float4*)out_col, F);
    } else {
        long long grid = (n + block - 1) / block;
        ifs_scalar_kernel<<<(dim3)(unsigned int)grid, block, 0, stream>>>(
            points, prev_colors, choices, matrices, biases, colors,
            out_tp, out_col, n);
    }
}